// Round 1
// baseline (1046.779 us; speedup 1.0000x reference)
//
#include <hip/hip_runtime.h>

#define B_ 64
#define L_ 128
#define V_ 100000
#define E_ 300
#define HD_ 200
#define H_ 400
#define S_ 50
#define START_ 48
#define END_ 49
#define NG_ 1600
#define G4_ 800
#define BL_ 8192

// ---- ws layout (bytes) ----
#define OFF_XG   0ull                        // bf16 [8192][1600]  26,214,400 B
#define OFF_LSTM (OFF_XG + 26214400ull)      // f32  [8192][400]   13,107,200 B
#define OFF_FEAT (OFF_LSTM + 13107200ull)    // f32  [8192][50]     1,638,400 B
#define OFF_WHH  (OFF_FEAT + 1638400ull)     // u32  [2][100][200][4]  640,000 B
#define OFF_WTT  (OFF_WHH + 640000ull)       // f32  [400][50]         80,000 B
#define OFF_ACC  (OFF_WTT + 80000ull)        // f32  [1]

__device__ __forceinline__ unsigned short f32_to_bf16(float f) {
    unsigned u = __float_as_uint(f);
    unsigned r = u + 0x7fffu + ((u >> 16) & 1u);
    return (unsigned short)(r >> 16);
}
__device__ __forceinline__ float bf16_to_f32(unsigned short s) {
    return __uint_as_float(((unsigned)s) << 16);
}
__device__ __forceinline__ float wlo(unsigned w) { return __uint_as_float(w << 16); }
__device__ __forceinline__ float whi(unsigned w) { return __uint_as_float(w & 0xffff0000u); }

// ---------------- prep: pack w_hh (both dirs) as transposed k-paired bf16, transpose W_tag, zero acc
__global__ void prep_kernel(const float* __restrict__ whh_f, const float* __restrict__ whh_b,
                            const float* __restrict__ wtag, float* __restrict__ wtagT,
                            unsigned* __restrict__ whhP, float* __restrict__ acc) {
    int g = blockIdx.x * 256 + threadIdx.x;
    if (g < 160000) {
        int dir = g / 80000;
        int rem = g % 80000;
        int kk2 = rem / 800;
        int r2  = rem % 800;
        int k = r2 >> 2;
        int q = r2 & 3;
        const float* w = dir ? whh_b : whh_f;
        int row = q * HD_ + k;
        float a = w[row * HD_ + 2 * kk2];
        float b = w[row * HD_ + 2 * kk2 + 1];
        whhP[g] = (unsigned)f32_to_bf16(a) | ((unsigned)f32_to_bf16(b) << 16);
    }
    if (g < 20000) {
        int k = g / S_, s = g % S_;
        wtagT[g] = wtag[s * H_ + k];
    }
    if (g == 0) acc[0] = 0.f;
}

// ---------------- xg GEMM: C[i,g] = sum_k emb[words[i],k] * W[g,k] + bias[g]  (fp32, bf16 out)
// W rows: g<800 -> w_ih_f[g], else w_ih_b[g-800]. Tile 128(M) x 64(N), BK=16, 256 thr, 8x4/thr.
__global__ __launch_bounds__(256) void xg_gemm(const int* __restrict__ words,
                                               const float* __restrict__ emb,
                                               const float* __restrict__ wihf,
                                               const float* __restrict__ wihb,
                                               const float* __restrict__ bf,
                                               const float* __restrict__ bb,
                                               unsigned short* __restrict__ xg) {
    __shared__ float As[16 * 129];
    __shared__ float Ws[16 * 65];
    __shared__ int wlds[128];
    int tid = threadIdx.x;
    int bm = blockIdx.y * 128;
    int bn = blockIdx.x * 64;
    if (tid < 128) wlds[tid] = words[bm + tid];
    __syncthreads();
    int tx = tid & 15, ty = tid >> 4;
    float acc[8][4];
#pragma unroll
    for (int a = 0; a < 8; ++a)
#pragma unroll
        for (int b1 = 0; b1 < 4; ++b1) acc[a][b1] = 0.f;

    int kk = tid & 15;
    int r0 = tid >> 4;
    for (int k0 = 0; k0 < 304; k0 += 16) {
        int k = k0 + kk;
        bool kv = (k < E_);
#pragma unroll
        for (int rep = 0; rep < 8; ++rep) {
            int row = r0 + rep * 16;
            float v = 0.f;
            if (kv) v = emb[wlds[row] * E_ + k];
            As[kk * 129 + row] = v;
        }
#pragma unroll
        for (int rep = 0; rep < 4; ++rep) {
            int gl = r0 + rep * 16;
            int g = bn + gl;
            float v = 0.f;
            if (kv) v = (g < G4_) ? wihf[g * E_ + k] : wihb[(g - G4_) * E_ + k];
            Ws[kk * 65 + gl] = v;
        }
        __syncthreads();
#pragma unroll
        for (int kki = 0; kki < 16; ++kki) {
            float av[8], bv[4];
#pragma unroll
            for (int a = 0; a < 8; ++a) av[a] = As[kki * 129 + ty + 16 * a];
#pragma unroll
            for (int b1 = 0; b1 < 4; ++b1) bv[b1] = Ws[kki * 65 + tx + 16 * b1];
#pragma unroll
            for (int a = 0; a < 8; ++a)
#pragma unroll
                for (int b1 = 0; b1 < 4; ++b1) acc[a][b1] = fmaf(av[a], bv[b1], acc[a][b1]);
        }
        __syncthreads();
    }
#pragma unroll
    for (int b1 = 0; b1 < 4; ++b1) {
        int g = bn + tx + 16 * b1;
        float bias = (g < G4_) ? bf[g] : bb[g - G4_];
#pragma unroll
        for (int a = 0; a < 8; ++a) {
            int i = bm + ty + 16 * a;
            xg[i * NG_ + g] = f32_to_bf16(acc[a][b1] + bias);
        }
    }
}

// ---------------- LSTM recurrence: block = (dir, batch). h in LDS, c in regs.
// whhP layout: [dir][kk2 (k-pair 0..99)][k_out 0..199][gate q 0..3] as packed bf16 pairs.
__global__ __launch_bounds__(256) void lstm_rec(const unsigned short* __restrict__ xg,
                                                const unsigned* __restrict__ whhP,
                                                float* __restrict__ lstm_out) {
    __shared__ __align__(16) float h[HD_];
    int tid = threadIdx.x;
    int dir = blockIdx.x >> 6;
    int b = blockIdx.x & 63;
    float c = 0.f;
    if (tid < HD_) h[tid] = 0.f;
    __syncthreads();
    const uint4* wp4 = ((const uint4*)whhP) + dir * 20000;
    const float2* h2 = (const float2*)h;
    float hn = 0.f;
    for (int step = 0; step < L_; ++step) {
        int t = dir ? (L_ - 1 - step) : step;
        if (tid < HD_) {
            const unsigned short* xr = xg + ((b * L_ + t) * NG_ + dir * G4_);
            float a0 = bf16_to_f32(xr[tid]);
            float a1 = bf16_to_f32(xr[HD_ + tid]);
            float a2 = bf16_to_f32(xr[2 * HD_ + tid]);
            float a3 = bf16_to_f32(xr[3 * HD_ + tid]);
#pragma unroll 4
            for (int kk2 = 0; kk2 < 100; ++kk2) {
                float2 hv = h2[kk2];
                uint4 w = wp4[kk2 * HD_ + tid];
                a0 = fmaf(wlo(w.x), hv.x, a0); a0 = fmaf(whi(w.x), hv.y, a0);
                a1 = fmaf(wlo(w.y), hv.x, a1); a1 = fmaf(whi(w.y), hv.y, a1);
                a2 = fmaf(wlo(w.z), hv.x, a2); a2 = fmaf(whi(w.z), hv.y, a2);
                a3 = fmaf(wlo(w.w), hv.x, a3); a3 = fmaf(whi(w.w), hv.y, a3);
            }
            float ig = 1.f / (1.f + __expf(-a0));
            float fg = 1.f / (1.f + __expf(-a1));
            float gg = tanhf(a2);
            float og = 1.f / (1.f + __expf(-a3));
            c = fg * c + ig * gg;
            hn = og * tanhf(c);
        }
        __syncthreads();
        if (tid < HD_) {
            h[tid] = hn;
            lstm_out[(b * L_ + t) * H_ + dir * HD_ + tid] = hn;
        }
        __syncthreads();
    }
}

// ---------------- features = lstm_out @ W_tag^T + b_tag  (uses transposed W_tagT [400][50])
__global__ __launch_bounds__(256) void feat_kernel(const float* __restrict__ lstm_out,
                                                   const float* __restrict__ wtagT,
                                                   const float* __restrict__ btag,
                                                   float* __restrict__ feats) {
    __shared__ float hrow[4 * H_];
    int tid = threadIdx.x;
    int base = blockIdx.x * 4;
    for (int idx = tid; idx < 4 * H_; idx += 256)
        hrow[idx] = lstm_out[base * H_ + idx];
    __syncthreads();
    int il = tid >> 6, s = tid & 63;
    if (s < S_) {
        float acc = btag[s];
        const float* hr = hrow + il * H_;
#pragma unroll 4
        for (int k = 0; k < H_; ++k)
            acc = fmaf(hr[k], wtagT[k * S_ + s], acc);
        feats[(base + il) * S_ + s] = acc;
    }
}

// ---------------- CRF forward + labeled score. Block = batch, 64 threads (1 wave).
__global__ __launch_bounds__(64) void crf_kernel(const float* __restrict__ feats,
                                                 const float* __restrict__ trans,
                                                 const int* __restrict__ tags,
                                                 const int* __restrict__ seqlens,
                                                 float* __restrict__ acc) {
    __shared__ float T[S_ * S_];
    __shared__ float alpha[S_];
    __shared__ float lastal[S_];
    __shared__ int tg[L_];
    int tid = threadIdx.x;
    int b = blockIdx.x;
    for (int idx = tid; idx < S_ * S_; idx += 64) T[idx] = trans[idx];
    for (int idx = tid; idx < L_; idx += 64) tg[idx] = tags[b * L_ + idx];
    int slen = seqlens[b];
    const float* fb = feats + b * L_ * S_;
    __syncthreads();
    bool act = (tid < S_);
    int j = tid;
    if (act) {
        float a = T[START_ * S_ + j] + fb[j];
        alpha[j] = a;
        if (slen == 1) lastal[j] = a;
    }
    __syncthreads();
    for (int t = 1; t < L_; ++t) {
        float a = 0.f;
        if (act) {
            float m = -1e30f;
            for (int i = 0; i < S_; ++i) m = fmaxf(m, alpha[i] + T[i * S_ + j]);
            float ssum = 0.f;
            for (int i = 0; i < S_; ++i) ssum += __expf(alpha[i] + T[i * S_ + j] - m);
            a = m + __logf(ssum) + fb[t * S_ + j];
        }
        __syncthreads();
        if (act) {
            alpha[j] = a;
            if (t == slen - 1) lastal[j] = a;
        }
        __syncthreads();
    }
    float la = act ? (lastal[j] + T[j * S_ + END_]) : -1e30f;
    float m = la;
    for (int off = 32; off; off >>= 1) m = fmaxf(m, __shfl_xor(m, off));
    float e = act ? __expf(la - m) : 0.f;
    for (int off = 32; off; off >>= 1) e += __shfl_xor(e, off);
    float unl = m + __logf(e);
    // labeled path
    float lab = 0.f;
    for (int tt = tid; tt < L_; tt += 64) {
        if (tt == 0) {
            lab += T[START_ * S_ + tg[0]] + fb[tg[0]];
        } else if (tt < slen) {
            lab += T[tg[tt - 1] * S_ + tg[tt]] + fb[tt * S_ + tg[tt]];
        }
    }
    if (tid == 0) lab += T[tg[slen - 1] * S_ + END_];
    for (int off = 32; off; off >>= 1) lab += __shfl_xor(lab, off);
    if (tid == 0) atomicAdd(acc, unl - lab);
}

__global__ void fin_kernel(const float* __restrict__ acc, float* __restrict__ out) {
    out[0] = acc[0];
}

extern "C" void kernel_launch(void* const* d_in, const int* in_sizes, int n_in,
                              void* d_out, int out_size, void* d_ws, size_t ws_size,
                              hipStream_t stream) {
    const int*   words = (const int*)d_in[0];
    const int*   slens = (const int*)d_in[1];
    // d_in[2] = masks: semantically (t < seq_len); not read (dtype-ambiguous bool).
    const int*   tags  = (const int*)d_in[3];
    const float* emb   = (const float*)d_in[4];
    const float* wihf  = (const float*)d_in[5];
    const float* whhf  = (const float*)d_in[6];
    const float* bf    = (const float*)d_in[7];
    const float* wihb  = (const float*)d_in[8];
    const float* whhb  = (const float*)d_in[9];
    const float* bb    = (const float*)d_in[10];
    const float* wtag  = (const float*)d_in[11];
    const float* btag  = (const float*)d_in[12];
    const float* trans = (const float*)d_in[13];

    char* ws = (char*)d_ws;
    unsigned short* xg   = (unsigned short*)(ws + OFF_XG);
    float*          lstm = (float*)(ws + OFF_LSTM);
    float*          fts  = (float*)(ws + OFF_FEAT);
    unsigned*       whhP = (unsigned*)(ws + OFF_WHH);
    float*          wtT  = (float*)(ws + OFF_WTT);
    float*          acc  = (float*)(ws + OFF_ACC);
    float*          out  = (float*)d_out;

    prep_kernel<<<625, 256, 0, stream>>>(whhf, whhb, wtag, wtT, whhP, acc);
    xg_gemm<<<dim3(25, 64), 256, 0, stream>>>(words, emb, wihf, wihb, bf, bb, xg);
    lstm_rec<<<128, 256, 0, stream>>>(xg, whhP, lstm);
    feat_kernel<<<2048, 256, 0, stream>>>(lstm, wtT, btag, fts);
    crf_kernel<<<64, 64, 0, stream>>>(fts, trans, tags, slens, acc);
    fin_kernel<<<1, 1, 0, stream>>>(acc, out);
}